// Round 9
// baseline (511.507 us; speedup 1.0000x reference)
//
#include <hip/hip_runtime.h>
#include <hip/hip_cooperative_groups.h>

namespace cg = cooperative_groups;

// ---------------------------------------------------------------------------
// JobSchedulerGNN round 9: single cooperative mega-kernel. Phases (verbatim
// R8 bodies) separated by grid.sync():
//   A: edge scatter->binned/boff | x->bf16 | weights->packed bf16
//   B: per-bucket CSR (deg/cursor/csr)
//   C: agg1 (8 lanes/node, 16-deep ILP)   D: gemm1 (LDS-A + packed-B MFMA)
//   E: agg2                               F: gemm2 + fused heads
// 16KB smem unioned across roles; __syncthreads() reuse-guard at role entry.
// ---------------------------------------------------------------------------

#define D 128
#define NPB 256
#define EPB 2048
#define BOFFW 257
#define RSTRIDE (4096 + 3 * NPB + 4)

typedef unsigned short ushort8 __attribute__((ext_vector_type(8)));
typedef __bf16 bf16x8 __attribute__((ext_vector_type(8)));
typedef float f32x4 __attribute__((ext_vector_type(4)));

__device__ inline unsigned short f2bf(float f) {
  unsigned u = __float_as_uint(f);
  u += 0x7FFFu + ((u >> 16) & 1u);  // RNE
  return (unsigned short)(u >> 16);
}
__device__ inline float bf2f(unsigned short h) {
  return __uint_as_float((unsigned)h << 16);
}

struct KP {
  const int* ei;
  const float* x;
  const float *s0, *s1, *s2, *s3;            // W1_rel, W1_root, W2_rel, W2_root
  const float *b1, *b2, *Wa, *ba, *Wo, *bo;
  float* out;
  unsigned short *xb, *aggb, *h1b;
  unsigned short *wp0, *wp1, *wp2, *wp3;     // packed weights
  int2* binned;
  int *boff, *deg, *cursor, *csr;
  int E, SC, total8, xB, NB, n, ablk, gblk;
};

// ---- aggregate role: 8 lanes/node x 16 bf16/lane, 8-row batches ------------
__device__ inline void aggRole(const KP& p, int vb,
                               const unsigned short* __restrict__ H,
                               unsigned short* __restrict__ out) {
  const int t = threadIdx.x;
  int node = vb * 32 + (t >> 3);
  if (node >= p.n) return;
  int f = (t & 7) * 16;
  int cnt = p.deg[node];
  int start = p.cursor[node] - cnt;  // padded start, start % 4 == 0
  float acc[16];
  #pragma unroll
  for (int e = 0; e < 16; e++) acc[e] = 0.f;
  const unsigned short* Hf = H + f;
  const int* csr = p.csr;
  int j = 0;
  for (; j + 8 <= cnt; j += 8) {
    int4 i0 = *(const int4*)&csr[start + j];
    int4 i1 = *(const int4*)&csr[start + j + 4];
    ushort8 a0 = *(const ushort8*)&Hf[(size_t)i0.x * D];
    ushort8 b0 = *(const ushort8*)&Hf[(size_t)i0.x * D + 8];
    ushort8 a1 = *(const ushort8*)&Hf[(size_t)i0.y * D];
    ushort8 b1 = *(const ushort8*)&Hf[(size_t)i0.y * D + 8];
    ushort8 a2 = *(const ushort8*)&Hf[(size_t)i0.z * D];
    ushort8 b2 = *(const ushort8*)&Hf[(size_t)i0.z * D + 8];
    ushort8 a3 = *(const ushort8*)&Hf[(size_t)i0.w * D];
    ushort8 b3 = *(const ushort8*)&Hf[(size_t)i0.w * D + 8];
    ushort8 a4 = *(const ushort8*)&Hf[(size_t)i1.x * D];
    ushort8 b4 = *(const ushort8*)&Hf[(size_t)i1.x * D + 8];
    ushort8 a5 = *(const ushort8*)&Hf[(size_t)i1.y * D];
    ushort8 b5 = *(const ushort8*)&Hf[(size_t)i1.y * D + 8];
    ushort8 a6 = *(const ushort8*)&Hf[(size_t)i1.z * D];
    ushort8 b6 = *(const ushort8*)&Hf[(size_t)i1.z * D + 8];
    ushort8 a7 = *(const ushort8*)&Hf[(size_t)i1.w * D];
    ushort8 b7 = *(const ushort8*)&Hf[(size_t)i1.w * D + 8];
    #pragma unroll
    for (int e = 0; e < 8; e++) {
      acc[e] += ((bf2f(a0[e]) + bf2f(a1[e])) + (bf2f(a2[e]) + bf2f(a3[e]))) +
                ((bf2f(a4[e]) + bf2f(a5[e])) + (bf2f(a6[e]) + bf2f(a7[e])));
      acc[8 + e] += ((bf2f(b0[e]) + bf2f(b1[e])) + (bf2f(b2[e]) + bf2f(b3[e]))) +
                    ((bf2f(b4[e]) + bf2f(b5[e])) + (bf2f(b6[e]) + bf2f(b7[e])));
    }
  }
  if (j + 4 <= cnt) {
    int4 i0 = *(const int4*)&csr[start + j];
    ushort8 a0 = *(const ushort8*)&Hf[(size_t)i0.x * D];
    ushort8 b0 = *(const ushort8*)&Hf[(size_t)i0.x * D + 8];
    ushort8 a1 = *(const ushort8*)&Hf[(size_t)i0.y * D];
    ushort8 b1 = *(const ushort8*)&Hf[(size_t)i0.y * D + 8];
    ushort8 a2 = *(const ushort8*)&Hf[(size_t)i0.z * D];
    ushort8 b2 = *(const ushort8*)&Hf[(size_t)i0.z * D + 8];
    ushort8 a3 = *(const ushort8*)&Hf[(size_t)i0.w * D];
    ushort8 b3 = *(const ushort8*)&Hf[(size_t)i0.w * D + 8];
    #pragma unroll
    for (int e = 0; e < 8; e++) {
      acc[e] += (bf2f(a0[e]) + bf2f(a1[e])) + (bf2f(a2[e]) + bf2f(a3[e]));
      acc[8 + e] += (bf2f(b0[e]) + bf2f(b1[e])) + (bf2f(b2[e]) + bf2f(b3[e]));
    }
    j += 4;
  }
  for (; j < cnt; j++) {
    int a = csr[start + j];
    ushort8 a0 = *(const ushort8*)&Hf[(size_t)a * D];
    ushort8 b0 = *(const ushort8*)&Hf[(size_t)a * D + 8];
    #pragma unroll
    for (int e = 0; e < 8; e++) {
      acc[e] += bf2f(a0[e]);
      acc[8 + e] += bf2f(b0[e]);
    }
  }
  ushort8 o0, o1;
  #pragma unroll
  for (int e = 0; e < 8; e++) { o0[e] = f2bf(acc[e]); o1[e] = f2bf(acc[8 + e]); }
  *(ushort8*)&out[(size_t)node * D + f] = o0;
  *(ushort8*)&out[(size_t)node * D + f + 8] = o1;
}

// ---- dual GEMM role: LDS-staged A (swizzled), packed coalesced B -----------
template <bool HEADS>
__device__ inline void gemmRole(const KP& p, int vb, char* smem,
                                const unsigned short* __restrict__ A1,
                                const unsigned short* __restrict__ P1,
                                const unsigned short* __restrict__ A2,
                                const unsigned short* __restrict__ P2,
                                const float* __restrict__ bias,
                                unsigned short* __restrict__ Cout) {
  unsigned short* sA = (unsigned short*)smem;  // 64*128 bf16 = 16KB
  const int tid = threadIdx.x;
  const int w = tid >> 6;
  const int l = tid & 63;
  const int lr = l & 15;
  const int kg = l >> 4;
  const int row0 = vb * 64;
  const int rl = w * 16 + lr;
  const int n = p.n;

  __syncthreads();  // smem reuse guard (previous iteration's reads)

  f32x4 acc[8];
  f32x4 zf = {0.f, 0.f, 0.f, 0.f};
  #pragma unroll
  for (int nr = 0; nr < 8; nr++) acc[nr] = zf;

  #pragma unroll
  for (int pass = 0; pass < 2; pass++) {
    const unsigned short* A = pass ? A2 : A1;
    const unsigned short* P = pass ? P2 : P1;
    if (pass) __syncthreads();
    #pragma unroll
    for (int i = 0; i < 4; i++) {
      int c = tid + i * 256;
      int row = c >> 4;
      int kc = c & 15;
      int grow = row0 + row;
      uint4 v = make_uint4(0u, 0u, 0u, 0u);
      if (grow < n) v = *(const uint4*)&A[(size_t)grow * D + kc * 8];
      int byte = (row * 256 + kc * 16) ^ ((row & 7) << 4);
      *(uint4*)((char*)sA + byte) = v;
    }
    __syncthreads();
    #pragma unroll
    for (int ks = 0; ks < 4; ks++) {
      int byte = (rl * 256 + (ks * 32 + kg * 8) * 2) ^ ((rl & 7) << 4);
      bf16x8 a = *(const bf16x8*)((const char*)sA + byte);
      #pragma unroll
      for (int nr = 0; nr < 8; nr++) {
        uint4 v = *(const uint4*)&P[(size_t)(((ks * 8 + nr) << 6) + l) * 8];
        acc[nr] = __builtin_amdgcn_mfma_f32_16x16x32_bf16(
            a, __builtin_bit_cast(bf16x8, v), acc[nr], 0, 0, 0);
      }
    }
  }

  float bcol[8];
  #pragma unroll
  for (int nr = 0; nr < 8; nr++) bcol[nr] = bias[nr * 16 + lr];

  if (!HEADS) {
    #pragma unroll
    for (int r = 0; r < 4; r++) {
      int row = row0 + w * 16 + kg * 4 + r;
      if (row < n) {
        #pragma unroll
        for (int nr = 0; nr < 8; nr++)
          Cout[(size_t)row * D + nr * 16 + lr] =
              f2bf(fmaxf(acc[nr][r] + bcol[nr], 0.f));
      }
    }
  } else {
    float pa0[4] = {0.f, 0.f, 0.f, 0.f};
    float pa1[4] = {0.f, 0.f, 0.f, 0.f};
    float po[4]  = {0.f, 0.f, 0.f, 0.f};
    #pragma unroll
    for (int nr = 0; nr < 8; nr++) {
      const int col = nr * 16 + lr;
      const float wa0 = p.Wa[col * 2 + 0];
      const float wa1 = p.Wa[col * 2 + 1];
      const float wo  = p.Wo[col];
      #pragma unroll
      for (int r = 0; r < 4; r++) {
        float hv = fmaxf(acc[nr][r] + bcol[nr], 0.f);
        pa0[r] += hv * wa0;
        pa1[r] += hv * wa1;
        po[r]  += hv * wo;
      }
    }
    #pragma unroll
    for (int off = 1; off < 16; off <<= 1) {
      #pragma unroll
      for (int r = 0; r < 4; r++) {
        pa0[r] += __shfl_xor(pa0[r], off);
        pa1[r] += __shfl_xor(pa1[r], off);
        po[r]  += __shfl_xor(po[r], off);
      }
    }
    if (lr == 0) {
      const float vba0 = p.ba[0], vba1 = p.ba[1], vbo = p.bo[0];
      #pragma unroll
      for (int r = 0; r < 4; r++) {
        int row = row0 + w * 16 + kg * 4 + r;
        if (row < n) {
          p.out[(size_t)row * 2 + 0] = pa0[r] + vba0;
          p.out[(size_t)row * 2 + 1] = pa1[r] + vba1;
          p.out[(size_t)2 * n + row] = po[r] + vbo;
        }
      }
    }
  }
}

// ---- the mega-kernel -------------------------------------------------------
__global__ __launch_bounds__(256, 4) void k_mega(KP p) {
  cg::grid_group grid = cg::this_grid();
  __shared__ __align__(16) char smem[16384];
  const int t = threadIdx.x;
  const int G = gridDim.x;

  // ---- Phase A: scatter | x-convert | w-convert ----
  const int tA = p.SC + p.xB + 256;
  for (int vb = blockIdx.x; vb < tA; vb += G) {
    if (vb < p.SC) {
      int* cnt = (int*)smem;
      int* base = (int*)smem + 256;
      __syncthreads();  // smem reuse guard
      cnt[t] = 0;
      __syncthreads();
      const int e0 = vb * EPB;
      int rs[8], rd[8];
      #pragma unroll
      for (int i = 0; i < 8; i++) {
        int e = e0 + i * 256 + t;
        if (e < p.E) {
          rs[i] = p.ei[e];
          rd[i] = p.ei[p.E + e];
          atomicAdd(&cnt[((unsigned)rd[i]) >> 8], 1);
        }
      }
      __syncthreads();
      int v = cnt[t];
      int incl = v;
      base[t] = incl;
      __syncthreads();
      #pragma unroll
      for (int off = 1; off < 256; off <<= 1) {
        int add = (t >= off) ? base[t - off] : 0;
        __syncthreads();
        incl += add;
        base[t] = incl;
        __syncthreads();
      }
      int ex = incl - v;
      p.boff[vb * BOFFW + t] = ex;
      if (t == 255) p.boff[vb * BOFFW + 256] = incl;
      base[t] = ex;
      __syncthreads();
      cnt[t] = 0;
      __syncthreads();
      #pragma unroll
      for (int i = 0; i < 8; i++) {
        int e = e0 + i * 256 + t;
        if (e < p.E) {
          int bk = ((unsigned)rd[i]) >> 8;
          int off = atomicAdd(&cnt[bk], 1);
          p.binned[(size_t)vb * EPB + base[bk] + off] = make_int2(rs[i], rd[i]);
        }
      }
    } else if (vb < p.SC + p.xB) {
      int i = (vb - p.SC) * 256 + t;
      if (i < p.total8) {
        const float4* q = (const float4*)(p.x + (size_t)i * 8);
        float4 v0 = q[0], v1 = q[1];
        ushort8 o;
        o[0] = f2bf(v0.x); o[1] = f2bf(v0.y); o[2] = f2bf(v0.z); o[3] = f2bf(v0.w);
        o[4] = f2bf(v1.x); o[5] = f2bf(v1.y); o[6] = f2bf(v1.z); o[7] = f2bf(v1.w);
        *(ushort8*)(p.xb + (size_t)i * 8) = o;
      }
    } else {
      int idx = (vb - p.SC - p.xB) * 256 + t;
      int mat = idx >> 14;
      int f = idx & 16383;
      int j = f & 7, l = (f >> 3) & 63, nr = (f >> 9) & 7, ks = f >> 12;
      int k = ks * 32 + (l >> 4) * 8 + j;
      int nn = nr * 16 + (l & 15);
      const float* s = (mat == 0) ? p.s0 : (mat == 1) ? p.s1 : (mat == 2) ? p.s2 : p.s3;
      unsigned short* d = (mat == 0) ? p.wp0 : (mat == 1) ? p.wp1 : (mat == 2) ? p.wp2 : p.wp3;
      d[f] = f2bf(s[k * 128 + nn]);
    }
  }
  grid.sync();

  // ---- Phase B: per-bucket CSR ----
  for (int vb = blockIdx.x; vb < p.NB; vb += G) {
    int* ldeg = (int*)smem;
    int* sd   = (int*)smem + 256;
    int* lcur = (int*)smem + 512;
    __syncthreads();  // smem reuse guard
    ldeg[t] = 0;
    __syncthreads();
    for (int blk = t; blk < p.SC; blk += 256) {
      int s = p.boff[blk * BOFFW + vb];
      int e = p.boff[blk * BOFFW + vb + 1];
      for (int i = s; i < e; i++) {
        int2 q = p.binned[(size_t)blk * EPB + i];
        atomicAdd(&ldeg[q.y & 255], 1);
      }
    }
    __syncthreads();
    const int dgr = ldeg[t];
    const int pd = (dgr + 3) & ~3;
    int incl = pd;
    sd[t] = incl;
    __syncthreads();
    #pragma unroll
    for (int off = 1; off < 256; off <<= 1) {
      int add = (t >= off) ? sd[t - off] : 0;
      __syncthreads();
      incl += add;
      sd[t] = incl;
      __syncthreads();
    }
    const int start = vb * RSTRIDE + (incl - pd);
    const int node = vb * 256 + t;
    if (node < p.n) {
      p.deg[node] = dgr;
      p.cursor[node] = start + dgr;
    }
    lcur[t] = start;
    __syncthreads();
    for (int blk = t; blk < p.SC; blk += 256) {
      int s = p.boff[blk * BOFFW + vb];
      int e = p.boff[blk * BOFFW + vb + 1];
      for (int i = s; i < e; i++) {
        int2 q = p.binned[(size_t)blk * EPB + i];
        int pos = atomicAdd(&lcur[q.y & 255], 1);
        p.csr[pos] = q.x;
      }
    }
  }
  grid.sync();

  // ---- Phase C: agg1 ----
  for (int vb = blockIdx.x; vb < p.ablk; vb += G) aggRole(p, vb, p.xb, p.aggb);
  grid.sync();
  // ---- Phase D: gemm1 ----
  for (int vb = blockIdx.x; vb < p.gblk; vb += G)
    gemmRole<false>(p, vb, smem, p.aggb, p.wp0, p.xb, p.wp1, p.b1, p.h1b);
  grid.sync();
  // ---- Phase E: agg2 ----
  for (int vb = blockIdx.x; vb < p.ablk; vb += G) aggRole(p, vb, p.h1b, p.aggb);
  grid.sync();
  // ---- Phase F: gemm2 + heads ----
  for (int vb = blockIdx.x; vb < p.gblk; vb += G)
    gemmRole<true>(p, vb, smem, p.aggb, p.wp2, p.h1b, p.wp3, p.b2, nullptr);
}

// ---- launch -----------------------------------------------------------------
extern "C" void kernel_launch(void* const* d_in, const int* in_sizes, int n_in,
                              void* d_out, int out_size, void* d_ws, size_t ws_size,
                              hipStream_t stream) {
  const int N = in_sizes[0] / D;
  const int E = in_sizes[1] / 2;
  const int NB = (N + NPB - 1) / NPB;
  const int SC = (E + EPB - 1) / EPB;

  char* w = (char*)d_ws;
  unsigned short* xb   = (unsigned short*)w; w += (size_t)N * D * 2;
  unsigned short* aggb = (unsigned short*)w; w += (size_t)N * D * 2;
  unsigned short* h1b  = (unsigned short*)w; w += (size_t)N * D * 2;
  unsigned short* WP0  = (unsigned short*)w; w += 128 * 128 * 2;
  unsigned short* WP1  = (unsigned short*)w; w += 128 * 128 * 2;
  unsigned short* WP2  = (unsigned short*)w; w += 128 * 128 * 2;
  unsigned short* WP3  = (unsigned short*)w; w += 128 * 128 * 2;
  int2* binned = (int2*)w; w += (size_t)SC * EPB * 8;
  int* boff    = (int*)w;  w += (size_t)SC * BOFFW * 4;
  int* deg     = (int*)w;  w += (size_t)N * 4;
  int* cursor  = (int*)w;  w += (size_t)N * 4;
  int* csr     = (int*)w;  w += (size_t)NB * RSTRIDE * 4;

  KP p;
  p.ei = (const int*)d_in[1];
  p.x  = (const float*)d_in[0];
  p.s0 = (const float*)d_in[2];   // W1_rel
  p.s1 = (const float*)d_in[4];   // W1_root
  p.s2 = (const float*)d_in[5];   // W2_rel
  p.s3 = (const float*)d_in[7];   // W2_root
  p.b1 = (const float*)d_in[3];
  p.b2 = (const float*)d_in[6];
  p.Wa = (const float*)d_in[8];
  p.ba = (const float*)d_in[9];
  p.Wo = (const float*)d_in[10];
  p.bo = (const float*)d_in[11];
  p.out = (float*)d_out;
  p.xb = xb; p.aggb = aggb; p.h1b = h1b;
  p.wp0 = WP0; p.wp1 = WP1; p.wp2 = WP2; p.wp3 = WP3;
  p.binned = binned; p.boff = boff;
  p.deg = deg; p.cursor = cursor; p.csr = csr;
  p.E = E; p.SC = SC; p.total8 = N * 16; p.xB = (N * 16 + 255) / 256;
  p.NB = NB; p.n = N;
  p.ablk = (N + 31) / 32;
  p.gblk = (N + 63) / 64;

  // co-residency sizing (pure host queries; capture-safe)
  int occ = 0;
  if (hipOccupancyMaxActiveBlocksPerMultiprocessor(&occ, (const void*)k_mega,
                                                   256, 0) != hipSuccess || occ < 1)
    occ = 2;
  int dev = 0, nCU = 256;
  hipGetDevice(&dev);
  hipDeviceGetAttribute(&nCU, hipDeviceAttributeMultiprocessorCount, dev);
  int grid = occ * nCU;
  if (grid > 1024) grid = 1024;

  void* args[] = {(void*)&p};
  hipLaunchCooperativeKernel((const void*)k_mega, dim3(grid), dim3(256), args,
                             0, stream);
}

// Round 10
// 118.562 us; speedup vs baseline: 4.3143x; 4.3143x over previous
//
#include <hip/hip_runtime.h>

// ---------------------------------------------------------------------------
// JobSchedulerGNN round 10: revert to R8 6-dispatch pipeline (mega-kernel
// spilled: 64 VGPR cap across merged roles -> 430MB scratch traffic).
// New: CSR rows padded to x4 with dummy index -> zero row (row N of xb/h1b,
// zeroed in prep). Aggregate loses its serial scalar tail entirely.
// 6 dispatches: fused_prep, bucket_csr, agg1, gemm1, agg2, gemm2+heads.
// ---------------------------------------------------------------------------

#define D 128
#define NPB 256                       // nodes per bucket (bucket=dst>>8)
#define EPB 2048                      // edges per scatter block
#define BOFFW 257                     // boff row width (256 scans + total)
#define RSTRIDE (4096 + 3 * NPB + 4)  // csr ints per bucket region

typedef unsigned short ushort8 __attribute__((ext_vector_type(8)));
typedef __bf16 bf16x8 __attribute__((ext_vector_type(8)));
typedef float f32x4 __attribute__((ext_vector_type(4)));

__device__ inline unsigned short f2bf(float f) {
  unsigned u = __float_as_uint(f);
  u += 0x7FFFu + ((u >> 16) & 1u);  // RNE
  return (unsigned short)(u >> 16);
}
__device__ inline float bf2f(unsigned short h) {
  return __uint_as_float((unsigned)h << 16);
}

// ---- fused: scatter | x-convert | w-convert (packed) | zero-rows -----------
// wpk layout per matrix: [((ks*8+nr)*64 + l)*8 + j] = W[ks*32+(l>>4)*8+j][nr*16+(l&15)]
__global__ __launch_bounds__(256) void k_fused_prep(
    const int* __restrict__ ei, int2* __restrict__ binned,
    int* __restrict__ boff, int E, int SC,
    const float* __restrict__ x, unsigned short* __restrict__ xb, int total8,
    int xB,
    const float* __restrict__ s0, const float* __restrict__ s1,
    const float* __restrict__ s2, const float* __restrict__ s3,
    unsigned short* __restrict__ d0, unsigned short* __restrict__ d1,
    unsigned short* __restrict__ d2, unsigned short* __restrict__ d3,
    unsigned short* __restrict__ h1b, int n) {
  const int b = blockIdx.x;
  const int t = threadIdx.x;
  if (b < SC) {  // ---- scatter role ----
    __shared__ int cnt[256], base[256];
    cnt[t] = 0;
    __syncthreads();
    const int e0 = b * EPB;
    int rs[8], rd[8];
    #pragma unroll
    for (int i = 0; i < 8; i++) {
      int e = e0 + i * 256 + t;
      if (e < E) {
        rs[i] = ei[e];
        rd[i] = ei[E + e];
        atomicAdd(&cnt[((unsigned)rd[i]) >> 8], 1);
      }
    }
    __syncthreads();
    int v = cnt[t];
    int incl = v;
    base[t] = incl;
    __syncthreads();
    #pragma unroll
    for (int off = 1; off < 256; off <<= 1) {
      int add = (t >= off) ? base[t - off] : 0;
      __syncthreads();
      incl += add;
      base[t] = incl;
      __syncthreads();
    }
    int ex = incl - v;
    boff[b * BOFFW + t] = ex;
    if (t == 255) boff[b * BOFFW + 256] = incl;  // total
    base[t] = ex;
    __syncthreads();
    cnt[t] = 0;
    __syncthreads();
    #pragma unroll
    for (int i = 0; i < 8; i++) {
      int e = e0 + i * 256 + t;
      if (e < E) {
        int bk = ((unsigned)rd[i]) >> 8;
        int off = atomicAdd(&cnt[bk], 1);
        binned[(size_t)b * EPB + base[bk] + off] = make_int2(rs[i], rd[i]);
      }
    }
  } else if (b < SC + xB) {  // ---- x -> bf16 ----
    int i = (b - SC) * 256 + t;
    if (i >= total8) return;
    const float4* p = (const float4*)(x + (size_t)i * 8);
    float4 v0 = p[0], v1 = p[1];
    ushort8 o;
    o[0] = f2bf(v0.x); o[1] = f2bf(v0.y); o[2] = f2bf(v0.z); o[3] = f2bf(v0.w);
    o[4] = f2bf(v1.x); o[5] = f2bf(v1.y); o[6] = f2bf(v1.z); o[7] = f2bf(v1.w);
    *(ushort8*)(xb + (size_t)i * 8) = o;
  } else if (b < SC + xB + 256) {  // ---- weights -> packed bf16 ----
    int idx = (b - SC - xB) * 256 + t;  // 0..65535
    int mat = idx >> 14;
    int f = idx & 16383;
    int j = f & 7, l = (f >> 3) & 63, nr = (f >> 9) & 7, ks = f >> 12;
    int k = ks * 32 + (l >> 4) * 8 + j;
    int nn = nr * 16 + (l & 15);
    const float* s = (mat == 0) ? s0 : (mat == 1) ? s1 : (mat == 2) ? s2 : s3;
    unsigned short* d = (mat == 0) ? d0 : (mat == 1) ? d1 : (mat == 2) ? d2 : d3;
    d[f] = f2bf(s[k * 128 + nn]);
  } else {  // ---- zero dummy rows (row N of xb and h1b) ----
    if (t < 128) xb[(size_t)n * D + t] = 0;
    else h1b[(size_t)n * D + (t - 128)] = 0;
  }
}

// ---- per-bucket CSR from per-block runs; rows padded to x4 with idx=n ------
__global__ __launch_bounds__(256) void k_bucket_csr(
    const int2* __restrict__ binned, const int* __restrict__ boff,
    int* __restrict__ deg, int* __restrict__ cursor, int* __restrict__ csr,
    int SC, int n) {
  __shared__ int ldeg[256], sd[256], lcur[256];
  const int b = blockIdx.x;
  const int t = threadIdx.x;
  ldeg[t] = 0;
  __syncthreads();
  for (int blk = t; blk < SC; blk += 256) {
    int s = boff[blk * BOFFW + b];
    int e = boff[blk * BOFFW + b + 1];
    for (int i = s; i < e; i++) {
      int2 p = binned[(size_t)blk * EPB + i];
      atomicAdd(&ldeg[p.y & 255], 1);
    }
  }
  __syncthreads();
  const int dgr = ldeg[t];
  const int pd = (dgr + 3) & ~3;
  int incl = pd;
  sd[t] = incl;
  __syncthreads();
  #pragma unroll
  for (int off = 1; off < 256; off <<= 1) {
    int add = (t >= off) ? sd[t - off] : 0;
    __syncthreads();
    incl += add;
    sd[t] = incl;
    __syncthreads();
  }
  const int start = b * RSTRIDE + (incl - pd);
  const int node = b * 256 + t;
  if (node < n) {
    deg[node] = dgr;
    cursor[node] = start + dgr;  // row end; aggregate does start = cursor-deg
  }
  // pad slots [start+dgr, start+pd) -> dummy zero-row index n
  for (int q = dgr; q < pd; q++) csr[start + q] = n;
  lcur[t] = start;
  __syncthreads();
  for (int blk = t; blk < SC; blk += 256) {
    int s = boff[blk * BOFFW + b];
    int e = boff[blk * BOFFW + b + 1];
    for (int i = s; i < e; i++) {
      int2 p = binned[(size_t)blk * EPB + i];
      int pos = atomicAdd(&lcur[p.y & 255], 1);
      csr[pos] = p.x;
    }
  }
}

// ---- aggregate: 8 lanes/node x 16 bf16/lane; padded rows -> NO scalar tail -
__global__ __launch_bounds__(256, 4) void k_aggregate(
    const unsigned short* __restrict__ H, const int* __restrict__ csr,
    const int* __restrict__ cursor, const int* __restrict__ deg,
    unsigned short* __restrict__ out, int n) {
  int t = threadIdx.x;
  int node = blockIdx.x * 32 + (t >> 3);
  if (node >= n) return;
  int f = (t & 7) * 16;
  int cnt = deg[node];
  int start = cursor[node] - cnt;        // padded start, start % 4 == 0
  int cntp = (cnt + 3) & ~3;             // padded count (pads read zero row)
  float acc[16];
  #pragma unroll
  for (int e = 0; e < 16; e++) acc[e] = 0.f;
  const unsigned short* Hf = H + f;
  int j = 0;
  for (; j + 8 <= cntp; j += 8) {
    int4 i0 = *(const int4*)&csr[start + j];
    int4 i1 = *(const int4*)&csr[start + j + 4];
    ushort8 a0 = *(const ushort8*)&Hf[(size_t)i0.x * D];
    ushort8 b0 = *(const ushort8*)&Hf[(size_t)i0.x * D + 8];
    ushort8 a1 = *(const ushort8*)&Hf[(size_t)i0.y * D];
    ushort8 b1 = *(const ushort8*)&Hf[(size_t)i0.y * D + 8];
    ushort8 a2 = *(const ushort8*)&Hf[(size_t)i0.z * D];
    ushort8 b2 = *(const ushort8*)&Hf[(size_t)i0.z * D + 8];
    ushort8 a3 = *(const ushort8*)&Hf[(size_t)i0.w * D];
    ushort8 b3 = *(const ushort8*)&Hf[(size_t)i0.w * D + 8];
    ushort8 a4 = *(const ushort8*)&Hf[(size_t)i1.x * D];
    ushort8 b4 = *(const ushort8*)&Hf[(size_t)i1.x * D + 8];
    ushort8 a5 = *(const ushort8*)&Hf[(size_t)i1.y * D];
    ushort8 b5 = *(const ushort8*)&Hf[(size_t)i1.y * D + 8];
    ushort8 a6 = *(const ushort8*)&Hf[(size_t)i1.z * D];
    ushort8 b6 = *(const ushort8*)&Hf[(size_t)i1.z * D + 8];
    ushort8 a7 = *(const ushort8*)&Hf[(size_t)i1.w * D];
    ushort8 b7 = *(const ushort8*)&Hf[(size_t)i1.w * D + 8];
    #pragma unroll
    for (int e = 0; e < 8; e++) {
      acc[e] += ((bf2f(a0[e]) + bf2f(a1[e])) + (bf2f(a2[e]) + bf2f(a3[e]))) +
                ((bf2f(a4[e]) + bf2f(a5[e])) + (bf2f(a6[e]) + bf2f(a7[e])));
      acc[8 + e] += ((bf2f(b0[e]) + bf2f(b1[e])) + (bf2f(b2[e]) + bf2f(b3[e]))) +
                    ((bf2f(b4[e]) + bf2f(b5[e])) + (bf2f(b6[e]) + bf2f(b7[e])));
    }
  }
  if (j < cntp) {  // exactly one 4-batch remains
    int4 i0 = *(const int4*)&csr[start + j];
    ushort8 a0 = *(const ushort8*)&Hf[(size_t)i0.x * D];
    ushort8 b0 = *(const ushort8*)&Hf[(size_t)i0.x * D + 8];
    ushort8 a1 = *(const ushort8*)&Hf[(size_t)i0.y * D];
    ushort8 b1 = *(const ushort8*)&Hf[(size_t)i0.y * D + 8];
    ushort8 a2 = *(const ushort8*)&Hf[(size_t)i0.z * D];
    ushort8 b2 = *(const ushort8*)&Hf[(size_t)i0.z * D + 8];
    ushort8 a3 = *(const ushort8*)&Hf[(size_t)i0.w * D];
    ushort8 b3 = *(const ushort8*)&Hf[(size_t)i0.w * D + 8];
    #pragma unroll
    for (int e = 0; e < 8; e++) {
      acc[e] += (bf2f(a0[e]) + bf2f(a1[e])) + (bf2f(a2[e]) + bf2f(a3[e]));
      acc[8 + e] += (bf2f(b0[e]) + bf2f(b1[e])) + (bf2f(b2[e]) + bf2f(b3[e]));
    }
  }
  ushort8 o0, o1;
  #pragma unroll
  for (int e = 0; e < 8; e++) { o0[e] = f2bf(acc[e]); o1[e] = f2bf(acc[8 + e]); }
  *(ushort8*)&out[(size_t)node * D + f] = o0;
  *(ushort8*)&out[(size_t)node * D + f + 8] = o1;
}

// ---- dual GEMM via MFMA: LDS-staged A (swizzled), packed coalesced B -------
// C = relu(A1@W1 + A2@W2 + bias). C/D layout: col=lane&15, row=(lane>>4)*4+reg.
template <bool HEADS>
__global__ __launch_bounds__(256, 4) void k_gemm(
    const unsigned short* __restrict__ A1, const unsigned short* __restrict__ P1,
    const unsigned short* __restrict__ A2, const unsigned short* __restrict__ P2,
    const float* __restrict__ bias, unsigned short* __restrict__ Cout,
    const float* __restrict__ Wa, const float* __restrict__ ba,
    const float* __restrict__ Wo, const float* __restrict__ bo,
    float* __restrict__ out, int n) {
  __shared__ __align__(16) unsigned short sA[64 * D];  // 16 KB, swizzled
  const int tid = threadIdx.x;
  const int w = tid >> 6;
  const int l = tid & 63;
  const int lr = l & 15;
  const int kg = l >> 4;
  const int row0 = blockIdx.x * 64;
  const int rl = w * 16 + lr;

  f32x4 acc[8];
  f32x4 zf = {0.f, 0.f, 0.f, 0.f};
  #pragma unroll
  for (int nr = 0; nr < 8; nr++) acc[nr] = zf;

  #pragma unroll
  for (int pass = 0; pass < 2; pass++) {
    const unsigned short* A = pass ? A2 : A1;
    const unsigned short* P = pass ? P2 : P1;
    if (pass) __syncthreads();  // protect sA reuse
    #pragma unroll
    for (int i = 0; i < 4; i++) {
      int c = tid + i * 256;      // chunk 0..1023
      int row = c >> 4;           // 0..63
      int kc = c & 15;            // 16B chunk in row
      int grow = row0 + row;
      uint4 v = make_uint4(0u, 0u, 0u, 0u);
      if (grow < n) v = *(const uint4*)&A[(size_t)grow * D + kc * 8];
      int byte = (row * 256 + kc * 16) ^ ((row & 7) << 4);
      *(uint4*)((char*)sA + byte) = v;
    }
    __syncthreads();
    #pragma unroll
    for (int ks = 0; ks < 4; ks++) {
      int byte = (rl * 256 + (ks * 32 + kg * 8) * 2) ^ ((rl & 7) << 4);
      bf16x8 a = *(const bf16x8*)((const char*)sA + byte);
      #pragma unroll
      for (int nr = 0; nr < 8; nr++) {
        uint4 v = *(const uint4*)&P[(size_t)(((ks * 8 + nr) << 6) + l) * 8];
        acc[nr] = __builtin_amdgcn_mfma_f32_16x16x32_bf16(
            a, __builtin_bit_cast(bf16x8, v), acc[nr], 0, 0, 0);
      }
    }
  }

  float bcol[8];
  #pragma unroll
  for (int nr = 0; nr < 8; nr++) bcol[nr] = bias[nr * 16 + lr];

  if (!HEADS) {
    #pragma unroll
    for (int r = 0; r < 4; r++) {
      int row = row0 + w * 16 + kg * 4 + r;
      if (row < n) {
        #pragma unroll
        for (int nr = 0; nr < 8; nr++)
          Cout[(size_t)row * D + nr * 16 + lr] =
              f2bf(fmaxf(acc[nr][r] + bcol[nr], 0.f));
      }
    }
  } else {
    float pa0[4] = {0.f, 0.f, 0.f, 0.f};
    float pa1[4] = {0.f, 0.f, 0.f, 0.f};
    float po[4]  = {0.f, 0.f, 0.f, 0.f};
    #pragma unroll
    for (int nr = 0; nr < 8; nr++) {
      const int col = nr * 16 + lr;
      const float wa0 = Wa[col * 2 + 0];
      const float wa1 = Wa[col * 2 + 1];
      const float wo  = Wo[col];
      #pragma unroll
      for (int r = 0; r < 4; r++) {
        float hv = fmaxf(acc[nr][r] + bcol[nr], 0.f);
        pa0[r] += hv * wa0;
        pa1[r] += hv * wa1;
        po[r]  += hv * wo;
      }
    }
    #pragma unroll
    for (int off = 1; off < 16; off <<= 1) {
      #pragma unroll
      for (int r = 0; r < 4; r++) {
        pa0[r] += __shfl_xor(pa0[r], off);
        pa1[r] += __shfl_xor(pa1[r], off);
        po[r]  += __shfl_xor(po[r], off);
      }
    }
    if (lr == 0) {
      const float vba0 = ba[0], vba1 = ba[1], vbo = bo[0];
      #pragma unroll
      for (int r = 0; r < 4; r++) {
        int row = row0 + w * 16 + kg * 4 + r;
        if (row < n) {
          out[(size_t)row * 2 + 0] = pa0[r] + vba0;
          out[(size_t)row * 2 + 1] = pa1[r] + vba1;
          out[(size_t)2 * n + row] = po[r] + vbo;
        }
      }
    }
  }
}

// ---- launch -----------------------------------------------------------------
extern "C" void kernel_launch(void* const* d_in, const int* in_sizes, int n_in,
                              void* d_out, int out_size, void* d_ws, size_t ws_size,
                              hipStream_t stream) {
  const float* x       = (const float*)d_in[0];
  const int*   ei      = (const int*)d_in[1];
  const float* W1_rel  = (const float*)d_in[2];
  const float* b1      = (const float*)d_in[3];
  const float* W1_root = (const float*)d_in[4];
  const float* W2_rel  = (const float*)d_in[5];
  const float* b2      = (const float*)d_in[6];
  const float* W2_root = (const float*)d_in[7];
  const float* Wa      = (const float*)d_in[8];
  const float* ba      = (const float*)d_in[9];
  const float* Wo      = (const float*)d_in[10];
  const float* bo      = (const float*)d_in[11];
  float* out = (float*)d_out;

  const int N = in_sizes[0] / D;
  const int E = in_sizes[1] / 2;
  const int NB = (N + NPB - 1) / NPB;   // 196 buckets for N=50000
  const int SC = (E + EPB - 1) / EPB;   // 293 scatter blocks

  char* w = (char*)d_ws;
  unsigned short* xb   = (unsigned short*)w; w += (size_t)(N + 1) * D * 2;  // +zero row
  unsigned short* aggb = (unsigned short*)w; w += (size_t)N * D * 2;
  unsigned short* h1b  = (unsigned short*)w; w += (size_t)(N + 1) * D * 2;  // +zero row
  unsigned short* WP1r = (unsigned short*)w; w += 128 * 128 * 2;
  unsigned short* WP1x = (unsigned short*)w; w += 128 * 128 * 2;
  unsigned short* WP2r = (unsigned short*)w; w += 128 * 128 * 2;
  unsigned short* WP2x = (unsigned short*)w; w += 128 * 128 * 2;
  int2* binned = (int2*)w; w += (size_t)SC * EPB * 8;
  int* boff    = (int*)w;  w += (size_t)SC * BOFFW * 4;
  int* deg     = (int*)w;  w += (size_t)N * 4;
  int* cursor  = (int*)w;  w += (size_t)N * 4;
  int* csr     = (int*)w;  w += (size_t)NB * RSTRIDE * 4;

  const int xB = (N * 16 + 255) / 256;

  k_fused_prep<<<SC + xB + 256 + 1, 256, 0, stream>>>(
      ei, binned, boff, E, SC, x, xb, N * 16, xB,
      W1_rel, W1_root, W2_rel, W2_root, WP1r, WP1x, WP2r, WP2x, h1b, N);
  k_bucket_csr<<<NB, 256, 0, stream>>>(binned, boff, deg, cursor, csr, SC, N);

  const int ablk = (N + 31) / 32;
  const int gblk = (N + 63) / 64;
  // layer 1: x -> h1
  k_aggregate<<<ablk, 256, 0, stream>>>(xb, csr, cursor, deg, aggb, N);
  k_gemm<false><<<gblk, 256, 0, stream>>>(
      aggb, WP1r, xb, WP1x, b1, h1b,
      nullptr, nullptr, nullptr, nullptr, nullptr, N);
  // layer 2 + heads: h1 -> out
  k_aggregate<<<ablk, 256, 0, stream>>>(h1b, csr, cursor, deg, aggb, N);
  k_gemm<true><<<gblk, 256, 0, stream>>>(
      aggb, WP2r, h1b, WP2x, b2, nullptr,
      Wa, ba, Wo, bo, out, N);
}

// Round 11
// 102.243 us; speedup vs baseline: 5.0028x; 1.1596x over previous
//
#include <hip/hip_runtime.h>

// ---------------------------------------------------------------------------
// JobSchedulerGNN round 11: 4-dispatch pipeline.
//   k_fused_prep : edge scatter->binned/boff | x->bf16 | weights->packed |
//                  zero dummy rows (unchanged from R10)
//   k_bucket_csr : per-bucket CSR w/ x4-padded rows (unchanged from R10)
//   k_agg_gemm<HEADS> x2 : per 32-node tile: ILP-16 gather -> swizzled LDS
//                  agg tile -> dual MFMA GEMM (LDS-agg@Wrel + H@Wroot + b,
//                  relu); wave(mr,ch) = 16-row x 64-col subtile; heads
//                  combined across col-half waves via LDS atomics.
// Kills the aggb round-trip (25.6MB) and 2 dispatches vs R10.
// ---------------------------------------------------------------------------

#define D 128
#define NPB 256                       // nodes per bucket (bucket=dst>>8)
#define EPB 2048                      // edges per scatter block
#define BOFFW 257                     // boff row width (256 scans + total)
#define RSTRIDE (4096 + 3 * NPB + 4)  // csr ints per bucket region

typedef unsigned short ushort8 __attribute__((ext_vector_type(8)));
typedef __bf16 bf16x8 __attribute__((ext_vector_type(8)));
typedef float f32x4 __attribute__((ext_vector_type(4)));

__device__ inline unsigned short f2bf(float f) {
  unsigned u = __float_as_uint(f);
  u += 0x7FFFu + ((u >> 16) & 1u);  // RNE
  return (unsigned short)(u >> 16);
}
__device__ inline float bf2f(unsigned short h) {
  return __uint_as_float((unsigned)h << 16);
}

// ---- fused: scatter | x-convert | w-convert (packed) | zero-rows -----------
// wpk layout per matrix: [((ks*8+nr)*64 + l)*8 + j] = W[ks*32+(l>>4)*8+j][nr*16+(l&15)]
__global__ __launch_bounds__(256) void k_fused_prep(
    const int* __restrict__ ei, int2* __restrict__ binned,
    int* __restrict__ boff, int E, int SC,
    const float* __restrict__ x, unsigned short* __restrict__ xb, int total8,
    int xB,
    const float* __restrict__ s0, const float* __restrict__ s1,
    const float* __restrict__ s2, const float* __restrict__ s3,
    unsigned short* __restrict__ d0, unsigned short* __restrict__ d1,
    unsigned short* __restrict__ d2, unsigned short* __restrict__ d3,
    unsigned short* __restrict__ h1b, int n) {
  const int b = blockIdx.x;
  const int t = threadIdx.x;
  if (b < SC) {  // ---- scatter role ----
    __shared__ int cnt[256], base[256];
    cnt[t] = 0;
    __syncthreads();
    const int e0 = b * EPB;
    int rs[8], rd[8];
    #pragma unroll
    for (int i = 0; i < 8; i++) {
      int e = e0 + i * 256 + t;
      if (e < E) {
        rs[i] = ei[e];
        rd[i] = ei[E + e];
        atomicAdd(&cnt[((unsigned)rd[i]) >> 8], 1);
      }
    }
    __syncthreads();
    int v = cnt[t];
    int incl = v;
    base[t] = incl;
    __syncthreads();
    #pragma unroll
    for (int off = 1; off < 256; off <<= 1) {
      int add = (t >= off) ? base[t - off] : 0;
      __syncthreads();
      incl += add;
      base[t] = incl;
      __syncthreads();
    }
    int ex = incl - v;
    boff[b * BOFFW + t] = ex;
    if (t == 255) boff[b * BOFFW + 256] = incl;  // total
    base[t] = ex;
    __syncthreads();
    cnt[t] = 0;
    __syncthreads();
    #pragma unroll
    for (int i = 0; i < 8; i++) {
      int e = e0 + i * 256 + t;
      if (e < E) {
        int bk = ((unsigned)rd[i]) >> 8;
        int off = atomicAdd(&cnt[bk], 1);
        binned[(size_t)b * EPB + base[bk] + off] = make_int2(rs[i], rd[i]);
      }
    }
  } else if (b < SC + xB) {  // ---- x -> bf16 ----
    int i = (b - SC) * 256 + t;
    if (i >= total8) return;
    const float4* p = (const float4*)(x + (size_t)i * 8);
    float4 v0 = p[0], v1 = p[1];
    ushort8 o;
    o[0] = f2bf(v0.x); o[1] = f2bf(v0.y); o[2] = f2bf(v0.z); o[3] = f2bf(v0.w);
    o[4] = f2bf(v1.x); o[5] = f2bf(v1.y); o[6] = f2bf(v1.z); o[7] = f2bf(v1.w);
    *(ushort8*)(xb + (size_t)i * 8) = o;
  } else if (b < SC + xB + 256) {  // ---- weights -> packed bf16 ----
    int idx = (b - SC - xB) * 256 + t;  // 0..65535
    int mat = idx >> 14;
    int f = idx & 16383;
    int j = f & 7, l = (f >> 3) & 63, nr = (f >> 9) & 7, ks = f >> 12;
    int k = ks * 32 + (l >> 4) * 8 + j;
    int nn = nr * 16 + (l & 15);
    const float* s = (mat == 0) ? s0 : (mat == 1) ? s1 : (mat == 2) ? s2 : s3;
    unsigned short* d = (mat == 0) ? d0 : (mat == 1) ? d1 : (mat == 2) ? d2 : d3;
    d[f] = f2bf(s[k * 128 + nn]);
  } else {  // ---- zero dummy rows (row N of xb and h1b) ----
    if (t < 128) xb[(size_t)n * D + t] = 0;
    else h1b[(size_t)n * D + (t - 128)] = 0;
  }
}

// ---- per-bucket CSR from per-block runs; rows padded to x4 with idx=n ------
__global__ __launch_bounds__(256) void k_bucket_csr(
    const int2* __restrict__ binned, const int* __restrict__ boff,
    int* __restrict__ deg, int* __restrict__ cursor, int* __restrict__ csr,
    int SC, int n) {
  __shared__ int ldeg[256], sd[256], lcur[256];
  const int b = blockIdx.x;
  const int t = threadIdx.x;
  ldeg[t] = 0;
  __syncthreads();
  for (int blk = t; blk < SC; blk += 256) {
    int s = boff[blk * BOFFW + b];
    int e = boff[blk * BOFFW + b + 1];
    for (int i = s; i < e; i++) {
      int2 p = binned[(size_t)blk * EPB + i];
      atomicAdd(&ldeg[p.y & 255], 1);
    }
  }
  __syncthreads();
  const int dgr = ldeg[t];
  const int pd = (dgr + 3) & ~3;
  int incl = pd;
  sd[t] = incl;
  __syncthreads();
  #pragma unroll
  for (int off = 1; off < 256; off <<= 1) {
    int add = (t >= off) ? sd[t - off] : 0;
    __syncthreads();
    incl += add;
    sd[t] = incl;
    __syncthreads();
  }
  const int start = b * RSTRIDE + (incl - pd);
  const int node = b * 256 + t;
  if (node < n) {
    deg[node] = dgr;
    cursor[node] = start + dgr;  // row end; aggregate does start = cursor-deg
  }
  // pad slots [start+dgr, start+pd) -> dummy zero-row index n
  for (int q = dgr; q < pd; q++) csr[start + q] = n;
  lcur[t] = start;
  __syncthreads();
  for (int blk = t; blk < SC; blk += 256) {
    int s = boff[blk * BOFFW + b];
    int e = boff[blk * BOFFW + b + 1];
    for (int i = s; i < e; i++) {
      int2 p = binned[(size_t)blk * EPB + i];
      int pos = atomicAdd(&lcur[p.y & 255], 1);
      csr[pos] = p.x;
    }
  }
}

// ---- fused aggregate + dual GEMM (+ heads) ---------------------------------
// 32 nodes/block. Gather: 8 lanes/node x 16 bf16, ILP-16, pad-free loop ->
// swizzled LDS tile. GEMM: wave(mr=w&1, ch=w>>1): rows mr*16..+15, col-tiles
// nr = ch*4..ch*4+3. K=256: pass0 A=LDS agg (B=Prel), pass1 A=H global
// (B=Proot). C/D layout: col=lane&15, row=(lane>>4)*4+reg.
template <bool HEADS>
__global__ __launch_bounds__(256, 4) void k_agg_gemm(
    const unsigned short* __restrict__ H,     // padded N+1 rows
    const unsigned short* __restrict__ Prel,
    const unsigned short* __restrict__ Proot,
    const int* __restrict__ csr, const int* __restrict__ cursor,
    const int* __restrict__ deg, const float* __restrict__ bias,
    unsigned short* __restrict__ Cout,
    const float* __restrict__ Wa, const float* __restrict__ ba,
    const float* __restrict__ Wo, const float* __restrict__ bo,
    float* __restrict__ out, int n) {
  __shared__ __align__(16) unsigned short sA[32 * D];  // 8 KB, swizzled
  __shared__ float sH[32][3];
  const int t = threadIdx.x;
  const int node32 = t >> 3;
  const int node = blockIdx.x * 32 + node32;
  const int f = (t & 7) * 16;

  if (HEADS) {
    if (t < 96) ((float*)sH)[t] = 0.f;
  }

  // ---- phase 1: gather (ILP-16) ----
  float acc[16];
  #pragma unroll
  for (int e = 0; e < 16; e++) acc[e] = 0.f;
  if (node < n) {
    int cnt = deg[node];
    int start = cursor[node] - cnt;    // padded start, %4==0
    int cntp = (cnt + 3) & ~3;
    const unsigned short* Hf = H + f;
    int j = 0;
    for (; j + 8 <= cntp; j += 8) {
      int4 i0 = *(const int4*)&csr[start + j];
      int4 i1 = *(const int4*)&csr[start + j + 4];
      ushort8 a0 = *(const ushort8*)&Hf[(size_t)i0.x * D];
      ushort8 b0 = *(const ushort8*)&Hf[(size_t)i0.x * D + 8];
      ushort8 a1 = *(const ushort8*)&Hf[(size_t)i0.y * D];
      ushort8 b1 = *(const ushort8*)&Hf[(size_t)i0.y * D + 8];
      ushort8 a2 = *(const ushort8*)&Hf[(size_t)i0.z * D];
      ushort8 b2 = *(const ushort8*)&Hf[(size_t)i0.z * D + 8];
      ushort8 a3 = *(const ushort8*)&Hf[(size_t)i0.w * D];
      ushort8 b3 = *(const ushort8*)&Hf[(size_t)i0.w * D + 8];
      ushort8 a4 = *(const ushort8*)&Hf[(size_t)i1.x * D];
      ushort8 b4 = *(const ushort8*)&Hf[(size_t)i1.x * D + 8];
      ushort8 a5 = *(const ushort8*)&Hf[(size_t)i1.y * D];
      ushort8 b5 = *(const ushort8*)&Hf[(size_t)i1.y * D + 8];
      ushort8 a6 = *(const ushort8*)&Hf[(size_t)i1.z * D];
      ushort8 b6 = *(const ushort8*)&Hf[(size_t)i1.z * D + 8];
      ushort8 a7 = *(const ushort8*)&Hf[(size_t)i1.w * D];
      ushort8 b7 = *(const ushort8*)&Hf[(size_t)i1.w * D + 8];
      #pragma unroll
      for (int e = 0; e < 8; e++) {
        acc[e] += ((bf2f(a0[e]) + bf2f(a1[e])) + (bf2f(a2[e]) + bf2f(a3[e]))) +
                  ((bf2f(a4[e]) + bf2f(a5[e])) + (bf2f(a6[e]) + bf2f(a7[e])));
        acc[8 + e] += ((bf2f(b0[e]) + bf2f(b1[e])) + (bf2f(b2[e]) + bf2f(b3[e]))) +
                      ((bf2f(b4[e]) + bf2f(b5[e])) + (bf2f(b6[e]) + bf2f(b7[e])));
      }
    }
    if (j < cntp) {  // exactly one 4-batch remains
      int4 i0 = *(const int4*)&csr[start + j];
      ushort8 a0 = *(const ushort8*)&Hf[(size_t)i0.x * D];
      ushort8 b0 = *(const ushort8*)&Hf[(size_t)i0.x * D + 8];
      ushort8 a1 = *(const ushort8*)&Hf[(size_t)i0.y * D];
      ushort8 b1 = *(const ushort8*)&Hf[(size_t)i0.y * D + 8];
      ushort8 a2 = *(const ushort8*)&Hf[(size_t)i0.z * D];
      ushort8 b2 = *(const ushort8*)&Hf[(size_t)i0.z * D + 8];
      ushort8 a3 = *(const ushort8*)&Hf[(size_t)i0.w * D];
      ushort8 b3 = *(const ushort8*)&Hf[(size_t)i0.w * D + 8];
      #pragma unroll
      for (int e = 0; e < 8; e++) {
        acc[e] += (bf2f(a0[e]) + bf2f(a1[e])) + (bf2f(a2[e]) + bf2f(a3[e]));
        acc[8 + e] += (bf2f(b0[e]) + bf2f(b1[e])) + (bf2f(b2[e]) + bf2f(b3[e]));
      }
    }
  }
  {  // write agg tile to swizzled LDS (zeros for OOB nodes)
    ushort8 o0, o1;
    #pragma unroll
    for (int e = 0; e < 8; e++) { o0[e] = f2bf(acc[e]); o1[e] = f2bf(acc[8 + e]); }
    const int sw = (node32 & 7) << 4;
    const int lin = node32 * 256 + (t & 7) * 32;
    *(uint4*)((char*)sA + (lin ^ sw)) = __builtin_bit_cast(uint4, o0);
    *(uint4*)((char*)sA + ((lin + 16) ^ sw)) = __builtin_bit_cast(uint4, o1);
  }
  __syncthreads();

  // ---- phase 2: dual GEMM ----
  const int w = t >> 6;
  const int mr = w & 1;
  const int ch = w >> 1;
  const int l = t & 63;
  const int lr = l & 15;
  const int kg = l >> 4;
  const int rl = mr * 16 + lr;

  f32x4 gacc[4];
  f32x4 zf = {0.f, 0.f, 0.f, 0.f};
  #pragma unroll
  for (int q = 0; q < 4; q++) gacc[q] = zf;

  // pass 0: A = LDS agg tile, B = Prel
  #pragma unroll
  for (int ks = 0; ks < 4; ks++) {
    int byte = (rl * 256 + (ks * 32 + kg * 8) * 2) ^ ((rl & 7) << 4);
    bf16x8 a = *(const bf16x8*)((const char*)sA + byte);
    #pragma unroll
    for (int q = 0; q < 4; q++) {
      int nr = ch * 4 + q;
      uint4 v = *(const uint4*)&Prel[(size_t)(((ks * 8 + nr) << 6) + l) * 8];
      gacc[q] = __builtin_amdgcn_mfma_f32_16x16x32_bf16(
          a, __builtin_bit_cast(bf16x8, v), gacc[q], 0, 0, 0);
    }
  }
  // pass 1: A = H rows (global), B = Proot
  const int grow = blockIdx.x * 32 + rl;
  #pragma unroll
  for (int ks = 0; ks < 4; ks++) {
    uint4 av = make_uint4(0u, 0u, 0u, 0u);
    if (grow < n) av = *(const uint4*)&H[(size_t)grow * D + ks * 32 + kg * 8];
    bf16x8 a = __builtin_bit_cast(bf16x8, av);
    #pragma unroll
    for (int q = 0; q < 4; q++) {
      int nr = ch * 4 + q;
      uint4 v = *(const uint4*)&Proot[(size_t)(((ks * 8 + nr) << 6) + l) * 8];
      gacc[q] = __builtin_amdgcn_mfma_f32_16x16x32_bf16(
          a, __builtin_bit_cast(bf16x8, v), gacc[q], 0, 0, 0);
    }
  }

  float bcol[4];
  #pragma unroll
  for (int q = 0; q < 4; q++) bcol[q] = bias[(ch * 4 + q) * 16 + lr];

  if (!HEADS) {
    #pragma unroll
    for (int r = 0; r < 4; r++) {
      int row = blockIdx.x * 32 + mr * 16 + kg * 4 + r;
      if (row < n) {
        #pragma unroll
        for (int q = 0; q < 4; q++)
          Cout[(size_t)row * D + (ch * 4 + q) * 16 + lr] =
              f2bf(fmaxf(gacc[q][r] + bcol[q], 0.f));
      }
    }
  } else {
    float pa0[4] = {0.f, 0.f, 0.f, 0.f};
    float pa1[4] = {0.f, 0.f, 0.f, 0.f};
    float po[4]  = {0.f, 0.f, 0.f, 0.f};
    #pragma unroll
    for (int q = 0; q < 4; q++) {
      const int col = (ch * 4 + q) * 16 + lr;
      const float wa0 = Wa[col * 2 + 0];
      const float wa1 = Wa[col * 2 + 1];
      const float wo  = Wo[col];
      #pragma unroll
      for (int r = 0; r < 4; r++) {
        float hv = fmaxf(gacc[q][r] + bcol[q], 0.f);
        pa0[r] += hv * wa0;
        pa1[r] += hv * wa1;
        po[r]  += hv * wo;
      }
    }
    #pragma unroll
    for (int off = 1; off < 16; off <<= 1) {
      #pragma unroll
      for (int r = 0; r < 4; r++) {
        pa0[r] += __shfl_xor(pa0[r], off);
        pa1[r] += __shfl_xor(pa1[r], off);
        po[r]  += __shfl_xor(po[r], off);
      }
    }
    if (lr == 0) {
      #pragma unroll
      for (int r = 0; r < 4; r++) {
        int lrow = mr * 16 + kg * 4 + r;
        atomicAdd(&sH[lrow][0], pa0[r]);
        atomicAdd(&sH[lrow][1], pa1[r]);
        atomicAdd(&sH[lrow][2], po[r]);
      }
    }
    __syncthreads();
    if (t < 32) {
      int row = blockIdx.x * 32 + t;
      if (row < n) {
        out[(size_t)row * 2 + 0] = sH[t][0] + ba[0];
        out[(size_t)row * 2 + 1] = sH[t][1] + ba[1];
        out[(size_t)2 * n + row] = sH[t][2] + bo[0];
      }
    }
  }
}

// ---- launch -----------------------------------------------------------------
extern "C" void kernel_launch(void* const* d_in, const int* in_sizes, int n_in,
                              void* d_out, int out_size, void* d_ws, size_t ws_size,
                              hipStream_t stream) {
  const float* x       = (const float*)d_in[0];
  const int*   ei      = (const int*)d_in[1];
  const float* W1_rel  = (const float*)d_in[2];
  const float* b1      = (const float*)d_in[3];
  const float* W1_root = (const float*)d_in[4];
  const float* W2_rel  = (const float*)d_in[5];
  const float* b2      = (const float*)d_in[6];
  const float* W2_root = (const float*)d_in[7];
  const float* Wa      = (const float*)d_in[8];
  const float* ba      = (const float*)d_in[9];
  const float* Wo      = (const float*)d_in[10];
  const float* bo      = (const float*)d_in[11];
  float* out = (float*)d_out;

  const int N = in_sizes[0] / D;
  const int E = in_sizes[1] / 2;
  const int NB = (N + NPB - 1) / NPB;   // 196 buckets for N=50000
  const int SC = (E + EPB - 1) / EPB;   // 293 scatter blocks

  char* w = (char*)d_ws;
  unsigned short* xb   = (unsigned short*)w; w += (size_t)(N + 1) * D * 2;  // +zero row
  unsigned short* h1b  = (unsigned short*)w; w += (size_t)(N + 1) * D * 2;  // +zero row
  unsigned short* WP1r = (unsigned short*)w; w += 128 * 128 * 2;
  unsigned short* WP1x = (unsigned short*)w; w += 128 * 128 * 2;
  unsigned short* WP2r = (unsigned short*)w; w += 128 * 128 * 2;
  unsigned short* WP2x = (unsigned short*)w; w += 128 * 128 * 2;
  int2* binned = (int2*)w; w += (size_t)SC * EPB * 8;
  int* boff    = (int*)w;  w += (size_t)SC * BOFFW * 4;
  int* deg     = (int*)w;  w += (size_t)N * 4;
  int* cursor  = (int*)w;  w += (size_t)N * 4;
  int* csr     = (int*)w;  w += (size_t)NB * RSTRIDE * 4;

  const int xB = (N * 16 + 255) / 256;

  k_fused_prep<<<SC + xB + 256 + 1, 256, 0, stream>>>(
      ei, binned, boff, E, SC, x, xb, N * 16, xB,
      W1_rel, W1_root, W2_rel, W2_root, WP1r, WP1x, WP2r, WP2x, h1b, N);
  k_bucket_csr<<<NB, 256, 0, stream>>>(binned, boff, deg, cursor, csr, SC, N);

  const int fblk = (N + 31) / 32;
  // layer 1: x -> h1 (fused gather+GEMM)
  k_agg_gemm<false><<<fblk, 256, 0, stream>>>(
      xb, WP1r, WP1x, csr, cursor, deg, b1, h1b,
      nullptr, nullptr, nullptr, nullptr, nullptr, N);
  // layer 2 + heads: h1 -> out (fused gather+GEMM+heads)
  k_agg_gemm<true><<<fblk, 256, 0, stream>>>(
      h1b, WP2r, WP2x, csr, cursor, deg, b2, nullptr,
      Wa, ba, Wo, bo, out, N);
}

// Round 12
// 101.384 us; speedup vs baseline: 5.0453x; 1.0085x over previous
//
#include <hip/hip_runtime.h>

// ---------------------------------------------------------------------------
// JobSchedulerGNN round 12 (vs R11):
//  - binned packed u32: src | (dst&255)<<16  (halves binning traffic)
//  - csr u16 (halves index traffic; dummy idx = n < 65536)
//  - x->bf16 conversion moved into the bucket_csr dispatch (overlaps the
//    LDS-atomic-bound CSR build with HBM streaming)
// 4 dispatches: prep(scatter|weights|zero), csr+xconv, agg_gemm1, agg_gemm2.
// ---------------------------------------------------------------------------

#define D 128
#define NPB 256                       // nodes per bucket (bucket=dst>>8)
#define EPB 2048                      // edges per scatter block
#define BOFFW 257                     // boff row width (256 scans + total)
#define RSTRIDE 4868                  // csr u16 per bucket (4096+3*256+4, %4==0)

typedef unsigned short ushort8 __attribute__((ext_vector_type(8)));
typedef __bf16 bf16x8 __attribute__((ext_vector_type(8)));
typedef float f32x4 __attribute__((ext_vector_type(4)));

__device__ inline unsigned short f2bf(float f) {
  unsigned u = __float_as_uint(f);
  u += 0x7FFFu + ((u >> 16) & 1u);  // RNE
  return (unsigned short)(u >> 16);
}
__device__ inline float bf2f(unsigned short h) {
  return __uint_as_float((unsigned)h << 16);
}

// ---- prep: scatter | w-convert (packed) | zero-rows ------------------------
// wpk layout per matrix: [((ks*8+nr)*64 + l)*8 + j] = W[ks*32+(l>>4)*8+j][nr*16+(l&15)]
__global__ __launch_bounds__(256) void k_prep(
    const int* __restrict__ ei, unsigned* __restrict__ binned,
    int* __restrict__ boff, int E, int SC,
    const float* __restrict__ s0, const float* __restrict__ s1,
    const float* __restrict__ s2, const float* __restrict__ s3,
    unsigned short* __restrict__ d0, unsigned short* __restrict__ d1,
    unsigned short* __restrict__ d2, unsigned short* __restrict__ d3,
    unsigned short* __restrict__ xb, unsigned short* __restrict__ h1b, int n) {
  const int b = blockIdx.x;
  const int t = threadIdx.x;
  if (b < SC) {  // ---- scatter role ----
    __shared__ int cnt[256], base[256];
    cnt[t] = 0;
    __syncthreads();
    const int e0 = b * EPB;
    int rs[8], rd[8];
    #pragma unroll
    for (int i = 0; i < 8; i++) {
      int e = e0 + i * 256 + t;
      if (e < E) {
        rs[i] = ei[e];
        rd[i] = ei[E + e];
        atomicAdd(&cnt[((unsigned)rd[i]) >> 8], 1);
      }
    }
    __syncthreads();
    int v = cnt[t];
    int incl = v;
    base[t] = incl;
    __syncthreads();
    #pragma unroll
    for (int off = 1; off < 256; off <<= 1) {
      int add = (t >= off) ? base[t - off] : 0;
      __syncthreads();
      incl += add;
      base[t] = incl;
      __syncthreads();
    }
    int ex = incl - v;
    boff[b * BOFFW + t] = ex;
    if (t == 255) boff[b * BOFFW + 256] = incl;  // total
    base[t] = ex;
    __syncthreads();
    cnt[t] = 0;
    __syncthreads();
    #pragma unroll
    for (int i = 0; i < 8; i++) {
      int e = e0 + i * 256 + t;
      if (e < E) {
        int bk = ((unsigned)rd[i]) >> 8;
        int off = atomicAdd(&cnt[bk], 1);
        binned[(size_t)b * EPB + base[bk] + off] =
            (unsigned)rs[i] | ((unsigned)(rd[i] & 255) << 16);
      }
    }
  } else if (b < SC + 256) {  // ---- weights -> packed bf16 ----
    int idx = (b - SC) * 256 + t;  // 0..65535
    int mat = idx >> 14;
    int f = idx & 16383;
    int j = f & 7, l = (f >> 3) & 63, nr = (f >> 9) & 7, ks = f >> 12;
    int k = ks * 32 + (l >> 4) * 8 + j;
    int nn = nr * 16 + (l & 15);
    const float* s = (mat == 0) ? s0 : (mat == 1) ? s1 : (mat == 2) ? s2 : s3;
    unsigned short* d = (mat == 0) ? d0 : (mat == 1) ? d1 : (mat == 2) ? d2 : d3;
    d[f] = f2bf(s[k * 128 + nn]);
  } else {  // ---- zero dummy rows (row N of xb and h1b) ----
    if (t < 128) xb[(size_t)n * D + t] = 0;
    else h1b[(size_t)n * D + (t - 128)] = 0;
  }
}

// ---- bucket CSR (u16, x4-padded rows, dummy=n) | x->bf16 -------------------
__global__ __launch_bounds__(256) void k_csr_xconv(
    const unsigned* __restrict__ binned, const int* __restrict__ boff,
    int* __restrict__ deg, int* __restrict__ cursor,
    unsigned short* __restrict__ csr, int SC, int n, int NB,
    const float* __restrict__ x, unsigned short* __restrict__ xb, int total8) {
  const int b = blockIdx.x;
  const int t = threadIdx.x;
  if (b < NB) {  // ---- bucket CSR role ----
    __shared__ int ldeg[256], sd[256], lcur[256];
    ldeg[t] = 0;
    __syncthreads();
    for (int blk = t; blk < SC; blk += 256) {
      int s = boff[blk * BOFFW + b];
      int e = boff[blk * BOFFW + b + 1];
      for (int i = s; i < e; i++) {
        unsigned pk = binned[(size_t)blk * EPB + i];
        atomicAdd(&ldeg[(pk >> 16) & 255], 1);
      }
    }
    __syncthreads();
    const int dgr = ldeg[t];
    const int pd = (dgr + 3) & ~3;
    int incl = pd;
    sd[t] = incl;
    __syncthreads();
    #pragma unroll
    for (int off = 1; off < 256; off <<= 1) {
      int add = (t >= off) ? sd[t - off] : 0;
      __syncthreads();
      incl += add;
      sd[t] = incl;
      __syncthreads();
    }
    const int start = b * RSTRIDE + (incl - pd);
    const int node = b * 256 + t;
    if (node < n) {
      deg[node] = dgr;
      cursor[node] = start + dgr;  // row end; gather does start = cursor-deg
    }
    for (int q = dgr; q < pd; q++) csr[start + q] = (unsigned short)n;
    lcur[t] = start;
    __syncthreads();
    for (int blk = t; blk < SC; blk += 256) {
      int s = boff[blk * BOFFW + b];
      int e = boff[blk * BOFFW + b + 1];
      for (int i = s; i < e; i++) {
        unsigned pk = binned[(size_t)blk * EPB + i];
        int pos = atomicAdd(&lcur[(pk >> 16) & 255], 1);
        csr[pos] = (unsigned short)(pk & 0xFFFFu);
      }
    }
  } else {  // ---- x -> bf16 role ----
    int i = (b - NB) * 256 + t;
    if (i >= total8) return;
    const float4* p = (const float4*)(x + (size_t)i * 8);
    float4 v0 = p[0], v1 = p[1];
    ushort8 o;
    o[0] = f2bf(v0.x); o[1] = f2bf(v0.y); o[2] = f2bf(v0.z); o[3] = f2bf(v0.w);
    o[4] = f2bf(v1.x); o[5] = f2bf(v1.y); o[6] = f2bf(v1.z); o[7] = f2bf(v1.w);
    *(ushort8*)(xb + (size_t)i * 8) = o;
  }
}

// ---- fused aggregate + dual GEMM (+ heads) ---------------------------------
// 32 nodes/block. Gather: 8 lanes/node x 16 bf16, ILP-16, u16 indices ->
// swizzled LDS tile. GEMM: wave(mr=w&1, ch=w>>1): rows mr*16..+15, col-tiles
// nr = ch*4..ch*4+3. K=256: pass0 A=LDS agg (B=Prel), pass1 A=H global
// (B=Proot). C/D layout: col=lane&15, row=(lane>>4)*4+reg.
template <bool HEADS>
__global__ __launch_bounds__(256, 4) void k_agg_gemm(
    const unsigned short* __restrict__ H,     // padded N+1 rows
    const unsigned short* __restrict__ Prel,
    const unsigned short* __restrict__ Proot,
    const unsigned short* __restrict__ csr, const int* __restrict__ cursor,
    const int* __restrict__ deg, const float* __restrict__ bias,
    unsigned short* __restrict__ Cout,
    const float* __restrict__ Wa, const float* __restrict__ ba,
    const float* __restrict__ Wo, const float* __restrict__ bo,
    float* __restrict__ out, int n) {
  __shared__ __align__(16) unsigned short sA[32 * D];  // 8 KB, swizzled
  __shared__ float sH[32][3];
  const int t = threadIdx.x;
  const int node32 = t >> 3;
  const int node = blockIdx.x * 32 + node32;
  const int f = (t & 7) * 16;

  if (HEADS) {
    if (t < 96) ((float*)sH)[t] = 0.f;
  }

  // ---- phase 1: gather (ILP-16) ----
  float acc[16];
  #pragma unroll
  for (int e = 0; e < 16; e++) acc[e] = 0.f;
  if (node < n) {
    int cnt = deg[node];
    int start = cursor[node] - cnt;    // padded start, %4==0
    int cntp = (cnt + 3) & ~3;
    const unsigned short* Hf = H + f;
    int j = 0;
    for (; j + 8 <= cntp; j += 8) {
      uint2 q0 = *(const uint2*)&csr[start + j];       // 4 u16 idx
      uint2 q1 = *(const uint2*)&csr[start + j + 4];   // 4 u16 idx
      unsigned i0 = q0.x & 0xFFFFu, i1 = q0.x >> 16;
      unsigned i2 = q0.y & 0xFFFFu, i3 = q0.y >> 16;
      unsigned i4 = q1.x & 0xFFFFu, i5 = q1.x >> 16;
      unsigned i6 = q1.y & 0xFFFFu, i7 = q1.y >> 16;
      ushort8 a0 = *(const ushort8*)&Hf[(size_t)i0 * D];
      ushort8 b0 = *(const ushort8*)&Hf[(size_t)i0 * D + 8];
      ushort8 a1 = *(const ushort8*)&Hf[(size_t)i1 * D];
      ushort8 b1 = *(const ushort8*)&Hf[(size_t)i1 * D + 8];
      ushort8 a2 = *(const ushort8*)&Hf[(size_t)i2 * D];
      ushort8 b2 = *(const ushort8*)&Hf[(size_t)i2 * D + 8];
      ushort8 a3 = *(const ushort8*)&Hf[(size_t)i3 * D];
      ushort8 b3 = *(const ushort8*)&Hf[(size_t)i3 * D + 8];
      ushort8 a4 = *(const ushort8*)&Hf[(size_t)i4 * D];
      ushort8 b4 = *(const ushort8*)&Hf[(size_t)i4 * D + 8];
      ushort8 a5 = *(const ushort8*)&Hf[(size_t)i5 * D];
      ushort8 b5 = *(const ushort8*)&Hf[(size_t)i5 * D + 8];
      ushort8 a6 = *(const ushort8*)&Hf[(size_t)i6 * D];
      ushort8 b6 = *(const ushort8*)&Hf[(size_t)i6 * D + 8];
      ushort8 a7 = *(const ushort8*)&Hf[(size_t)i7 * D];
      ushort8 b7 = *(const ushort8*)&Hf[(size_t)i7 * D + 8];
      #pragma unroll
      for (int e = 0; e < 8; e++) {
        acc[e] += ((bf2f(a0[e]) + bf2f(a1[e])) + (bf2f(a2[e]) + bf2f(a3[e]))) +
                  ((bf2f(a4[e]) + bf2f(a5[e])) + (bf2f(a6[e]) + bf2f(a7[e])));
        acc[8 + e] += ((bf2f(b0[e]) + bf2f(b1[e])) + (bf2f(b2[e]) + bf2f(b3[e]))) +
                      ((bf2f(b4[e]) + bf2f(b5[e])) + (bf2f(b6[e]) + bf2f(b7[e])));
      }
    }
    if (j < cntp) {  // exactly one 4-batch remains
      uint2 q0 = *(const uint2*)&csr[start + j];
      unsigned i0 = q0.x & 0xFFFFu, i1 = q0.x >> 16;
      unsigned i2 = q0.y & 0xFFFFu, i3 = q0.y >> 16;
      ushort8 a0 = *(const ushort8*)&Hf[(size_t)i0 * D];
      ushort8 b0 = *(const ushort8*)&Hf[(size_t)i0 * D + 8];
      ushort8 a1 = *(const ushort8*)&Hf[(size_t)i1 * D];
      ushort8 b1 = *(const ushort8*)&Hf[(size_t)i1 * D + 8];
      ushort8 a2 = *(const ushort8*)&Hf[(size_t)i2 * D];
      ushort8 b2 = *(const ushort8*)&Hf[(size_t)i2 * D + 8];
      ushort8 a3 = *(const ushort8*)&Hf[(size_t)i3 * D];
      ushort8 b3 = *(const ushort8*)&Hf[(size_t)i3 * D + 8];
      #pragma unroll
      for (int e = 0; e < 8; e++) {
        acc[e] += (bf2f(a0[e]) + bf2f(a1[e])) + (bf2f(a2[e]) + bf2f(a3[e]));
        acc[8 + e] += (bf2f(b0[e]) + bf2f(b1[e])) + (bf2f(b2[e]) + bf2f(b3[e]));
      }
    }
  }
  {  // write agg tile to swizzled LDS (zeros for OOB nodes)
    ushort8 o0, o1;
    #pragma unroll
    for (int e = 0; e < 8; e++) { o0[e] = f2bf(acc[e]); o1[e] = f2bf(acc[8 + e]); }
    const int sw = (node32 & 7) << 4;
    const int lin = node32 * 256 + (t & 7) * 32;
    *(uint4*)((char*)sA + (lin ^ sw)) = __builtin_bit_cast(uint4, o0);
    *(uint4*)((char*)sA + ((lin + 16) ^ sw)) = __builtin_bit_cast(uint4, o1);
  }
  __syncthreads();

  // ---- phase 2: dual GEMM ----
  const int w = t >> 6;
  const int mr = w & 1;
  const int ch = w >> 1;
  const int l = t & 63;
  const int lr = l & 15;
  const int kg = l >> 4;
  const int rl = mr * 16 + lr;

  f32x4 gacc[4];
  f32x4 zf = {0.f, 0.f, 0.f, 0.f};
  #pragma unroll
  for (int q = 0; q < 4; q++) gacc[q] = zf;

  // pass 0: A = LDS agg tile, B = Prel
  #pragma unroll
  for (int ks = 0; ks < 4; ks++) {
    int byte = (rl * 256 + (ks * 32 + kg * 8) * 2) ^ ((rl & 7) << 4);
    bf16x8 a = *(const bf16x8*)((const char*)sA + byte);
    #pragma unroll
    for (int q = 0; q < 4; q++) {
      int nr = ch * 4 + q;
      uint4 v = *(const uint4*)&Prel[(size_t)(((ks * 8 + nr) << 6) + l) * 8];
      gacc[q] = __builtin_amdgcn_mfma_f32_16x16x32_bf16(
          a, __builtin_bit_cast(bf16x8, v), gacc[q], 0, 0, 0);
    }
  }
  // pass 1: A = H rows (global), B = Proot
  const int grow = blockIdx.x * 32 + rl;
  #pragma unroll
  for (int ks = 0; ks < 4; ks++) {
    uint4 av = make_uint4(0u, 0u, 0u, 0u);
    if (grow < n) av = *(const uint4*)&H[(size_t)grow * D + ks * 32 + kg * 8];
    bf16x8 a = __builtin_bit_cast(bf16x8, av);
    #pragma unroll
    for (int q = 0; q < 4; q++) {
      int nr = ch * 4 + q;
      uint4 v = *(const uint4*)&Proot[(size_t)(((ks * 8 + nr) << 6) + l) * 8];
      gacc[q] = __builtin_amdgcn_mfma_f32_16x16x32_bf16(
          a, __builtin_bit_cast(bf16x8, v), gacc[q], 0, 0, 0);
    }
  }

  float bcol[4];
  #pragma unroll
  for (int q = 0; q < 4; q++) bcol[q] = bias[(ch * 4 + q) * 16 + lr];

  if (!HEADS) {
    #pragma unroll
    for (int r = 0; r < 4; r++) {
      int row = blockIdx.x * 32 + mr * 16 + kg * 4 + r;
      if (row < n) {
        #pragma unroll
        for (int q = 0; q < 4; q++)
          Cout[(size_t)row * D + (ch * 4 + q) * 16 + lr] =
              f2bf(fmaxf(gacc[q][r] + bcol[q], 0.f));
      }
    }
  } else {
    float pa0[4] = {0.f, 0.f, 0.f, 0.f};
    float pa1[4] = {0.f, 0.f, 0.f, 0.f};
    float po[4]  = {0.f, 0.f, 0.f, 0.f};
    #pragma unroll
    for (int q = 0; q < 4; q++) {
      const int col = (ch * 4 + q) * 16 + lr;
      const float wa0 = Wa[col * 2 + 0];
      const float wa1 = Wa[col * 2 + 1];
      const float wo  = Wo[col];
      #pragma unroll
      for (int r = 0; r < 4; r++) {
        float hv = fmaxf(gacc[q][r] + bcol[q], 0.f);
        pa0[r] += hv * wa0;
        pa1[r] += hv * wa1;
        po[r]  += hv * wo;
      }
    }
    #pragma unroll
    for (int off = 1; off < 16; off <<= 1) {
      #pragma unroll
      for (int r = 0; r < 4; r++) {
        pa0[r] += __shfl_xor(pa0[r], off);
        pa1[r] += __shfl_xor(pa1[r], off);
        po[r]  += __shfl_xor(po[r], off);
      }
    }
    if (lr == 0) {
      #pragma unroll
      for (int r = 0; r < 4; r++) {
        int lrow = mr * 16 + kg * 4 + r;
        atomicAdd(&sH[lrow][0], pa0[r]);
        atomicAdd(&sH[lrow][1], pa1[r]);
        atomicAdd(&sH[lrow][2], po[r]);
      }
    }
    __syncthreads();
    if (t < 32) {
      int row = blockIdx.x * 32 + t;
      if (row < n) {
        out[(size_t)row * 2 + 0] = sH[t][0] + ba[0];
        out[(size_t)row * 2 + 1] = sH[t][1] + ba[1];
        out[(size_t)2 * n + row] = sH[t][2] + bo[0];
      }
    }
  }
}

// ---- launch -----------------------------------------------------------------
extern "C" void kernel_launch(void* const* d_in, const int* in_sizes, int n_in,
                              void* d_out, int out_size, void* d_ws, size_t ws_size,
                              hipStream_t stream) {
  const float* x       = (const float*)d_in[0];
  const int*   ei      = (const int*)d_in[1];
  const float* W1_rel  = (const float*)d_in[2];
  const float* b1      = (const float*)d_in[3];
  const float* W1_root = (const float*)d_in[4];
  const float* W2_rel  = (const float*)d_in[5];
  const float* b2      = (const float*)d_in[6];
  const float* W2_root = (const float*)d_in[7];
  const float* Wa      = (const float*)d_in[8];
  const float* ba      = (const float*)d_in[9];
  const float* Wo      = (const float*)d_in[10];
  const float* bo      = (const float*)d_in[11];
  float* out = (float*)d_out;

  const int N = in_sizes[0] / D;
  const int E = in_sizes[1] / 2;
  const int NB = (N + NPB - 1) / NPB;   // 196 buckets for N=50000
  const int SC = (E + EPB - 1) / EPB;   // 293 scatter blocks

  char* w = (char*)d_ws;
  unsigned short* xb   = (unsigned short*)w; w += (size_t)(N + 1) * D * 2;  // +zero row
  unsigned short* h1b  = (unsigned short*)w; w += (size_t)(N + 1) * D * 2;  // +zero row
  unsigned short* WP1r = (unsigned short*)w; w += 128 * 128 * 2;
  unsigned short* WP1x = (unsigned short*)w; w += 128 * 128 * 2;
  unsigned short* WP2r = (unsigned short*)w; w += 128 * 128 * 2;
  unsigned short* WP2x = (unsigned short*)w; w += 128 * 128 * 2;
  unsigned* binned = (unsigned*)w; w += (size_t)SC * EPB * 4;
  int* boff    = (int*)w;  w += (size_t)SC * BOFFW * 4;
  int* deg     = (int*)w;  w += (size_t)N * 4;
  int* cursor  = (int*)w;  w += (size_t)N * 4;
  unsigned short* csr = (unsigned short*)w; w += (size_t)NB * RSTRIDE * 2;

  const int xB = (N * 16 + 255) / 256;

  k_prep<<<SC + 256 + 1, 256, 0, stream>>>(
      ei, binned, boff, E, SC,
      W1_rel, W1_root, W2_rel, W2_root, WP1r, WP1x, WP2r, WP2x, xb, h1b, N);
  k_csr_xconv<<<NB + xB, 256, 0, stream>>>(
      binned, boff, deg, cursor, csr, SC, N, NB, x, xb, N * 16);

  const int fblk = (N + 31) / 32;
  // layer 1: x -> h1 (fused gather+GEMM)
  k_agg_gemm<false><<<fblk, 256, 0, stream>>>(
      xb, WP1r, WP1x, csr, cursor, deg, b1, h1b,
      nullptr, nullptr, nullptr, nullptr, nullptr, N);
  // layer 2 + heads: h1 -> out (fused gather+GEMM+heads)
  k_agg_gemm<true><<<fblk, 256, 0, stream>>>(
      h1b, WP2r, WP2x, csr, cursor, deg, b2, nullptr,
      Wa, ba, Wo, bo, out, N);
}